// Round 1
// baseline (1235.012 us; speedup 1.0000x reference)
//
#include <hip/hip_runtime.h>
#include <math.h>

// MS-SSIM, 5 levels, fp32, N=32 images of 512x512 (single channel).
// Strategy: per level, one fused tiled kernel does the separable 11x11
// Gaussian blur of (x1, x2, x1^2, x2^2, x1*x2) via LDS, computes the
// ssim/mcs maps per pixel, block-reduces and atomically accumulates
// per-level sums. A pool kernel builds the 2x downsampled pyramid in d_ws.
// A 1-thread finalize kernel computes the weighted product.

#define TILE 16
#define HALO 5
#define SW (TILE + 2 * HALO)  // 26

struct GaussW { float w[11]; };

#define C1_ (0.01f * 0.01f)
#define C2_ (0.03f * 0.03f)

__global__ void ssim_level_kernel(const float* __restrict__ img1,
                                  const float* __restrict__ img2,
                                  int H, int W,
                                  float* __restrict__ acc,  // acc[0]=ssim_sum, acc[1]=mcs_sum
                                  GaussW gw) {
    __shared__ float s1[SW * SW];
    __shared__ float s2[SW * SW];
    __shared__ float hbuf[5][SW][TILE];
    __shared__ float red_s[4], red_m[4];

    const int tid = threadIdx.x;            // 0..255
    const int tx = tid & (TILE - 1);
    const int ty = tid / TILE;
    const int tile_x = blockIdx.x * TILE;
    const int tile_y = blockIdx.y * TILE;
    const size_t img_off = (size_t)blockIdx.z * (size_t)H * (size_t)W;
    const float* p1 = img1 + img_off;
    const float* p2 = img2 + img_off;

    // --- load halo tile (zero padding outside image) ---
    for (int i = tid; i < SW * SW; i += 256) {
        int r = i / SW, c = i % SW;
        int gy = tile_y + r - HALO;
        int gx = tile_x + c - HALO;
        float v1 = 0.f, v2 = 0.f;
        if (gy >= 0 && gy < H && gx >= 0 && gx < W) {
            v1 = p1[(size_t)gy * W + gx];
            v2 = p2[(size_t)gy * W + gx];
        }
        s1[i] = v1;
        s2[i] = v2;
    }
    __syncthreads();

    // --- horizontal blur of the 5 channels (26 rows x 16 out-cols) ---
    for (int i = tid; i < SW * TILE; i += 256) {
        int r = i / TILE, c = i % TILE;
        float b1 = 0.f, b2 = 0.f, b11 = 0.f, b22 = 0.f, b12 = 0.f;
#pragma unroll
        for (int k = 0; k < 11; k++) {
            float wk = gw.w[k];
            float a1 = s1[r * SW + c + k];
            float a2 = s2[r * SW + c + k];
            b1  += wk * a1;
            b2  += wk * a2;
            b11 += wk * a1 * a1;
            b22 += wk * a2 * a2;
            b12 += wk * a1 * a2;
        }
        hbuf[0][r][c] = b1;
        hbuf[1][r][c] = b2;
        hbuf[2][r][c] = b11;
        hbuf[3][r][c] = b22;
        hbuf[4][r][c] = b12;
    }
    __syncthreads();

    // --- vertical blur + ssim/mcs for this thread's output pixel ---
    float ssim_v = 0.f, mcs_v = 0.f;
    int gx = tile_x + tx;
    int gy = tile_y + ty;
    if (gx < W && gy < H) {
        float mu1 = 0.f, mu2 = 0.f, m11 = 0.f, m22 = 0.f, m12 = 0.f;
#pragma unroll
        for (int k = 0; k < 11; k++) {
            float wk = gw.w[k];
            mu1 += wk * hbuf[0][ty + k][tx];
            mu2 += wk * hbuf[1][ty + k][tx];
            m11 += wk * hbuf[2][ty + k][tx];
            m22 += wk * hbuf[3][ty + k][tx];
            m12 += wk * hbuf[4][ty + k][tx];
        }
        float mu1sq = mu1 * mu1;
        float mu2sq = mu2 * mu2;
        float mu12  = mu1 * mu2;
        float sg11 = m11 - mu1sq;
        float sg22 = m22 - mu2sq;
        float sg12 = m12 - mu12;
        float mcs  = (2.f * sg12 + C2_) / (sg11 + sg22 + C2_);
        float ssim = ((2.f * mu12 + C1_) / (mu1sq + mu2sq + C1_)) * mcs;
        ssim_v = ssim;
        mcs_v = mcs;
    }

    // --- block reduction (4 waves of 64) ---
#pragma unroll
    for (int off = 32; off > 0; off >>= 1) {
        ssim_v += __shfl_down(ssim_v, off);
        mcs_v  += __shfl_down(mcs_v, off);
    }
    int wave = tid >> 6, lane = tid & 63;
    if (lane == 0) { red_s[wave] = ssim_v; red_m[wave] = mcs_v; }
    __syncthreads();
    if (tid == 0) {
        float S = red_s[0] + red_s[1] + red_s[2] + red_s[3];
        float M = red_m[0] + red_m[1] + red_m[2] + red_m[3];
        atomicAdd(&acc[0], S);
        atomicAdd(&acc[1], M);
    }
}

// 2x2 average pool on both images at once. total = N*Ho*Wo.
__global__ void pool2_kernel(const float* __restrict__ in1,
                             const float* __restrict__ in2,
                             float* __restrict__ out1,
                             float* __restrict__ out2,
                             int Ho, int Wo, int total) {
    int idx = blockIdx.x * blockDim.x + threadIdx.x;
    if (idx >= total) return;
    int x = idx % Wo;
    int y = (idx / Wo) % Ho;
    int n = idx / (Wo * Ho);
    int Wi = Wo * 2;
    size_t ib = (size_t)n * (size_t)(4 * Ho * Wo) + (size_t)(2 * y) * Wi + 2 * x;
    float a = in1[ib], b = in1[ib + 1], c = in1[ib + Wi], d = in1[ib + Wi + 1];
    out1[idx] = 0.25f * (a + b + c + d);
    float e = in2[ib], f = in2[ib + 1], g = in2[ib + Wi], h = in2[ib + Wi + 1];
    out2[idx] = 0.25f * (e + f + g + h);
}

__global__ void finalize_kernel(const float* __restrict__ acc,
                                float* __restrict__ out, int N) {
    if (threadIdx.x == 0 && blockIdx.x == 0) {
        const float wts[5] = {0.0448f, 0.2856f, 0.3001f, 0.2363f, 0.1333f};
        float r = 1.f;
#pragma unroll
        for (int l = 0; l < 5; l++) {
            int Hl = 512 >> l;
            float cnt = (float)N * (float)Hl * (float)Hl;
            float ssim_m = acc[2 * l] / cnt;
            float mcs_m  = acc[2 * l + 1] / cnt;
            if (l < 4) r *= powf(mcs_m, wts[l]);
            else       r *= powf(ssim_m, wts[4]);
        }
        out[0] = r;
    }
}

extern "C" void kernel_launch(void* const* d_in, const int* in_sizes, int n_in,
                              void* d_out, int out_size, void* d_ws, size_t ws_size,
                              hipStream_t stream) {
    const float* img1 = (const float*)d_in[0];
    const float* img2 = (const float*)d_in[1];
    float* out = (float*)d_out;
    const int HW0 = 512 * 512;
    const int N = in_sizes[0] / HW0;  // 32

    // ws layout: [0..63] accumulator floats (10 used), then pyramid buffers.
    float* base = (float*)d_ws;
    float* acc = base;
    size_t cur = 64;
    const float* l1[5];
    const float* l2[5];
    float* w1[5] = {nullptr};
    float* w2[5] = {nullptr};
    l1[0] = img1;
    l2[0] = img2;
    for (int l = 1; l < 5; l++) {
        int Hl = 512 >> l;
        size_t hw = (size_t)Hl * Hl;
        w1[l] = base + cur; cur += (size_t)N * hw;
        w2[l] = base + cur; cur += (size_t)N * hw;
        l1[l] = w1[l];
        l2[l] = w2[l];
    }

    // zero the accumulators (ws is poisoned before every timed launch)
    hipMemsetAsync(acc, 0, 16 * sizeof(float), stream);

    // gaussian window (computed on host each call; cheap, capture-safe)
    GaussW gw;
    {
        double g[11], sum = 0.0;
        for (int i = 0; i < 11; i++) {
            double x = (double)(i - 5);
            g[i] = exp(-(x * x) / (2.0 * 1.5 * 1.5));
            sum += g[i];
        }
        for (int i = 0; i < 11; i++) gw.w[i] = (float)(g[i] / sum);
    }

    for (int l = 0; l < 5; l++) {
        int Hl = 512 >> l;
        dim3 grid((Hl + TILE - 1) / TILE, (Hl + TILE - 1) / TILE, N);
        ssim_level_kernel<<<grid, 256, 0, stream>>>(l1[l], l2[l], Hl, Hl,
                                                    acc + 2 * l, gw);
        if (l < 4) {
            int Ho = Hl / 2;
            int total = N * Ho * Ho;
            pool2_kernel<<<(total + 255) / 256, 256, 0, stream>>>(
                l1[l], l2[l], w1[l + 1], w2[l + 1], Ho, Ho, total);
        }
    }
    finalize_kernel<<<1, 64, 0, stream>>>(acc, out, N);
}

// Round 2
// 262.895 us; speedup vs baseline: 4.6977x; 4.6977x over previous
//
#include <hip/hip_runtime.h>
#include <math.h>

// MS-SSIM, 5 levels, fp32, N=32 images of 512x512 (single channel).
// R2: (a) spread per-block atomic accumulation across 64 slots per quantity
//     (round-1 was serialized ~25ns/block on a single contended cache line),
//     (b) 32x32 output tiles (4 px/thread, 256 threads) to cut block count 4x
//     and halo over-fetch from 1.9x to 1.7x.

#define TILE 32
#define HALO 5
#define SW (TILE + 2 * HALO)  // 42
#define NSLOT 64

struct GaussW { float w[11]; };

#define C1_ (0.01f * 0.01f)
#define C2_ (0.03f * 0.03f)

__global__ __launch_bounds__(256) void ssim_level_kernel(
        const float* __restrict__ img1,
        const float* __restrict__ img2,
        int H, int W,
        float* __restrict__ acc,  // [2][NSLOT]: ssim slots then mcs slots
        GaussW gw) {
    __shared__ float s1[SW * SW];
    __shared__ float s2[SW * SW];
    __shared__ float hbuf[5][SW][TILE];
    __shared__ float red_s[4], red_m[4];

    const int tid = threadIdx.x;            // 0..255
    const int tx = tid & (TILE - 1);        // 0..31
    const int ty4 = tid >> 5;               // 0..7, each handles 4 rows
    const int tile_x = blockIdx.x * TILE;
    const int tile_y = blockIdx.y * TILE;
    const size_t img_off = (size_t)blockIdx.z * (size_t)H * (size_t)W;
    const float* p1 = img1 + img_off;
    const float* p2 = img2 + img_off;

    // --- load halo tile (zero padding outside image) ---
    for (int i = tid; i < SW * SW; i += 256) {
        int r = i / SW, c = i % SW;
        int gy = tile_y + r - HALO;
        int gx = tile_x + c - HALO;
        float v1 = 0.f, v2 = 0.f;
        if (gy >= 0 && gy < H && gx >= 0 && gx < W) {
            v1 = p1[(size_t)gy * W + gx];
            v2 = p2[(size_t)gy * W + gx];
        }
        s1[i] = v1;
        s2[i] = v2;
    }
    __syncthreads();

    // --- horizontal blur of the 5 channels (42 rows x 32 out-cols) ---
    for (int i = tid; i < SW * TILE; i += 256) {
        int r = i >> 5, c = i & 31;
        float b1 = 0.f, b2 = 0.f, b11 = 0.f, b22 = 0.f, b12 = 0.f;
#pragma unroll
        for (int k = 0; k < 11; k++) {
            float wk = gw.w[k];
            float a1 = s1[r * SW + c + k];
            float a2 = s2[r * SW + c + k];
            b1  += wk * a1;
            b2  += wk * a2;
            b11 += wk * a1 * a1;
            b22 += wk * a2 * a2;
            b12 += wk * a1 * a2;
        }
        hbuf[0][r][c] = b1;
        hbuf[1][r][c] = b2;
        hbuf[2][r][c] = b11;
        hbuf[3][r][c] = b22;
        hbuf[4][r][c] = b12;
    }
    __syncthreads();

    // --- vertical blur + ssim/mcs for this thread's 4 output pixels ---
    float ssim_v = 0.f, mcs_v = 0.f;
    const int gx = tile_x + tx;
#pragma unroll
    for (int j = 0; j < 4; j++) {
        int y = ty4 * 4 + j;
        int gy = tile_y + y;
        if (gx < W && gy < H) {
            float mu1 = 0.f, mu2 = 0.f, m11 = 0.f, m22 = 0.f, m12 = 0.f;
#pragma unroll
            for (int k = 0; k < 11; k++) {
                float wk = gw.w[k];
                mu1 += wk * hbuf[0][y + k][tx];
                mu2 += wk * hbuf[1][y + k][tx];
                m11 += wk * hbuf[2][y + k][tx];
                m22 += wk * hbuf[3][y + k][tx];
                m12 += wk * hbuf[4][y + k][tx];
            }
            float mu1sq = mu1 * mu1;
            float mu2sq = mu2 * mu2;
            float mu12  = mu1 * mu2;
            float sg11 = m11 - mu1sq;
            float sg22 = m22 - mu2sq;
            float sg12 = m12 - mu12;
            float mcs  = (2.f * sg12 + C2_) / (sg11 + sg22 + C2_);
            float ssim = ((2.f * mu12 + C1_) / (mu1sq + mu2sq + C1_)) * mcs;
            ssim_v += ssim;
            mcs_v  += mcs;
        }
    }

    // --- block reduction (4 waves of 64) ---
#pragma unroll
    for (int off = 32; off > 0; off >>= 1) {
        ssim_v += __shfl_down(ssim_v, off);
        mcs_v  += __shfl_down(mcs_v, off);
    }
    int wave = tid >> 6, lane = tid & 63;
    if (lane == 0) { red_s[wave] = ssim_v; red_m[wave] = mcs_v; }
    __syncthreads();
    if (tid == 0) {
        float S = red_s[0] + red_s[1] + red_s[2] + red_s[3];
        float M = red_m[0] + red_m[1] + red_m[2] + red_m[3];
        unsigned lb = blockIdx.x + gridDim.x * (blockIdx.y + gridDim.y * blockIdx.z);
        unsigned slot = lb & (NSLOT - 1);
        atomicAdd(&acc[slot], S);
        atomicAdd(&acc[NSLOT + slot], M);
    }
}

// 2x2 average pool on both images at once. total = N*Ho*Wo.
__global__ void pool2_kernel(const float* __restrict__ in1,
                             const float* __restrict__ in2,
                             float* __restrict__ out1,
                             float* __restrict__ out2,
                             int Ho, int Wo, int total) {
    int idx = blockIdx.x * blockDim.x + threadIdx.x;
    if (idx >= total) return;
    int x = idx % Wo;
    int y = (idx / Wo) % Ho;
    int n = idx / (Wo * Ho);
    int Wi = Wo * 2;
    size_t ib = (size_t)n * (size_t)(4 * Ho * Wo) + (size_t)(2 * y) * Wi + 2 * x;
    float a = in1[ib], b = in1[ib + 1], c = in1[ib + Wi], d = in1[ib + Wi + 1];
    out1[idx] = 0.25f * (a + b + c + d);
    float e = in2[ib], f = in2[ib + 1], g = in2[ib + Wi], h = in2[ib + Wi + 1];
    out2[idx] = 0.25f * (e + f + g + h);
}

// acc layout: level l, quantity q (0=ssim,1=mcs) at acc[(2*l+q)*NSLOT + slot]
__global__ void finalize_kernel(const float* __restrict__ acc,
                                float* __restrict__ out, int N) {
    int lane = threadIdx.x & 63;
    float sums[10];
#pragma unroll
    for (int q = 0; q < 10; q++) {
        float v = acc[q * NSLOT + lane];
#pragma unroll
        for (int off = 32; off > 0; off >>= 1) v += __shfl_down(v, off);
        sums[q] = v;
    }
    if (lane == 0 && blockIdx.x == 0 && threadIdx.x == 0) {
        const float wts[5] = {0.0448f, 0.2856f, 0.3001f, 0.2363f, 0.1333f};
        float r = 1.f;
#pragma unroll
        for (int l = 0; l < 5; l++) {
            int Hl = 512 >> l;
            float cnt = (float)N * (float)Hl * (float)Hl;
            float ssim_m = sums[2 * l] / cnt;
            float mcs_m  = sums[2 * l + 1] / cnt;
            if (l < 4) r *= powf(mcs_m, wts[l]);
            else       r *= powf(ssim_m, wts[4]);
        }
        out[0] = r;
    }
}

extern "C" void kernel_launch(void* const* d_in, const int* in_sizes, int n_in,
                              void* d_out, int out_size, void* d_ws, size_t ws_size,
                              hipStream_t stream) {
    const float* img1 = (const float*)d_in[0];
    const float* img2 = (const float*)d_in[1];
    float* out = (float*)d_out;
    const int HW0 = 512 * 512;
    const int N = in_sizes[0] / HW0;  // 32

    // ws layout: accumulator slots (10*NSLOT floats), then pyramid buffers.
    float* base = (float*)d_ws;
    float* acc = base;
    size_t cur = 10 * NSLOT;
    const float* l1[5];
    const float* l2[5];
    float* w1[5] = {nullptr};
    float* w2[5] = {nullptr};
    l1[0] = img1;
    l2[0] = img2;
    for (int l = 1; l < 5; l++) {
        int Hl = 512 >> l;
        size_t hw = (size_t)Hl * Hl;
        w1[l] = base + cur; cur += (size_t)N * hw;
        w2[l] = base + cur; cur += (size_t)N * hw;
        l1[l] = w1[l];
        l2[l] = w2[l];
    }

    // zero the accumulator slots (ws is poisoned before every timed launch)
    hipMemsetAsync(acc, 0, 10 * NSLOT * sizeof(float), stream);

    // gaussian window (computed on host each call; cheap, capture-safe)
    GaussW gw;
    {
        double g[11], sum = 0.0;
        for (int i = 0; i < 11; i++) {
            double x = (double)(i - 5);
            g[i] = exp(-(x * x) / (2.0 * 1.5 * 1.5));
            sum += g[i];
        }
        for (int i = 0; i < 11; i++) gw.w[i] = (float)(g[i] / sum);
    }

    for (int l = 0; l < 5; l++) {
        int Hl = 512 >> l;
        dim3 grid((Hl + TILE - 1) / TILE, (Hl + TILE - 1) / TILE, N);
        ssim_level_kernel<<<grid, 256, 0, stream>>>(l1[l], l2[l], Hl, Hl,
                                                    acc + 2 * l * NSLOT, gw);
        if (l < 4) {
            int Ho = Hl / 2;
            int total = N * Ho * Ho;
            pool2_kernel<<<(total + 255) / 256, 256, 0, stream>>>(
                l1[l], l2[l], w1[l + 1], w2[l + 1], Ho, Ho, total);
        }
    }
    finalize_kernel<<<1, 64, 0, stream>>>(acc, out, N);
}

// Round 3
// 231.555 us; speedup vs baseline: 5.3336x; 1.1353x over previous
//
#include <hip/hip_runtime.h>
#include <math.h>

// MS-SSIM, 5 levels, fp32, N=32 images of 512x512 (single channel).
// R3: (a) horizontal blur via aligned float4 LDS reads + 16-float register
//     window (4 outputs/item, products computed once) — cuts scalar ds_read
//     and VALU addressing ~5x; (b) vertical blur via 14-row register sliding
//     window (70 reads vs 220); (c) 2x2 pool fused into the SSIM kernel
//     (tile already in LDS) — removes 4 dispatches + 84 MB HBM re-read.

#define TILE 32
#define HALO 5
#define SROWS (TILE + 2 * HALO)  // 42
#define SSTR 44                  // padded row stride (16B-aligned rows)
#define NSLOT 64

struct GaussW { float w[11]; };

#define C1_ (0.01f * 0.01f)
#define C2_ (0.03f * 0.03f)

__global__ __launch_bounds__(256, 3) void ssim_level_kernel(
        const float* __restrict__ img1,
        const float* __restrict__ img2,
        int W,                        // H == W, multiple of 32
        float* __restrict__ acc,      // [2][NSLOT]
        float* __restrict__ pool1,    // next-level img1 (nullptr at last level)
        float* __restrict__ pool2,
        GaussW gw) {
    __shared__ float s1[SROWS * SSTR];
    __shared__ float s2[SROWS * SSTR];
    __shared__ float hbuf[5][SROWS * TILE];
    __shared__ float red_s[4], red_m[4];

    const int tid = threadIdx.x;
    const int tile_x = blockIdx.x * TILE;
    const int tile_y = blockIdx.y * TILE;
    const size_t img_off = (size_t)blockIdx.z * (size_t)W * (size_t)W;
    const float* p1 = img1 + img_off;
    const float* p2 = img2 + img_off;

    // ---- stage 1: load halo tile (zero pad outside image; pad cols zeroed) ----
#pragma unroll
    for (int it = 0; it < 8; it++) {
        int i = tid + it * 256;
        if (i < SROWS * SSTR) {
            int r = i / SSTR, c = i - r * SSTR;
            int gy = tile_y + r - HALO;
            int gx = tile_x + c - HALO;
            float v1 = 0.f, v2 = 0.f;
            if (c < SROWS && gy >= 0 && gy < W && gx >= 0 && gx < W) {
                v1 = p1[(size_t)gy * W + gx];
                v2 = p2[(size_t)gy * W + gx];
            }
            s1[i] = v1;
            s2[i] = v2;
        }
    }
    __syncthreads();

    // ---- fused 2x2 avg pool for next level (256 threads = 16x16 outputs) ----
    if (pool1 != nullptr) {
        int xo = tid & 15, yo = tid >> 4;
        int rr = 2 * yo + HALO, cc = 2 * xo + HALO;
        const float* a = &s1[rr * SSTR + cc];
        float q1 = 0.25f * (a[0] + a[1] + a[SSTR] + a[SSTR + 1]);
        const float* b = &s2[rr * SSTR + cc];
        float q2 = 0.25f * (b[0] + b[1] + b[SSTR] + b[SSTR + 1]);
        int Wo = W >> 1;
        size_t o = (size_t)blockIdx.z * (size_t)Wo * Wo +
                   (size_t)((tile_y >> 1) + yo) * Wo + (size_t)((tile_x >> 1) + xo);
        pool1[o] = q1;
        pool2[o] = q2;
    }

    // ---- stage 2: horizontal blur, 4 consecutive outputs per item ----
    for (int it = tid; it < SROWS * 8; it += 256) {
        int r = it >> 3, c4 = it & 7;
        int base = r * SSTR + c4 * 4;
        float4 A0 = *(const float4*)&s1[base];
        float4 A1 = *(const float4*)&s1[base + 4];
        float4 A2 = *(const float4*)&s1[base + 8];
        float4 A3 = *(const float4*)&s1[base + 12];
        float4 B0 = *(const float4*)&s2[base];
        float4 B1 = *(const float4*)&s2[base + 4];
        float4 B2 = *(const float4*)&s2[base + 8];
        float4 B3 = *(const float4*)&s2[base + 12];
        float a1[16] = {A0.x, A0.y, A0.z, A0.w, A1.x, A1.y, A1.z, A1.w,
                        A2.x, A2.y, A2.z, A2.w, A3.x, A3.y, A3.z, A3.w};
        float a2[16] = {B0.x, B0.y, B0.z, B0.w, B1.x, B1.y, B1.z, B1.w,
                        B2.x, B2.y, B2.z, B2.w, B3.x, B3.y, B3.z, B3.w};
        float p11[14], p22[14], p12[14];
#pragma unroll
        for (int i = 0; i < 14; i++) {
            p11[i] = a1[i] * a1[i];
            p22[i] = a2[i] * a2[i];
            p12[i] = a1[i] * a2[i];
        }
        float h0[4] = {0, 0, 0, 0}, h1[4] = {0, 0, 0, 0}, h2[4] = {0, 0, 0, 0};
        float h3[4] = {0, 0, 0, 0}, h4[4] = {0, 0, 0, 0};
#pragma unroll
        for (int k = 0; k < 11; k++) {
            float wk = gw.w[k];
#pragma unroll
            for (int j = 0; j < 4; j++) {
                h0[j] += wk * a1[j + k];
                h1[j] += wk * a2[j + k];
                h2[j] += wk * p11[j + k];
                h3[j] += wk * p22[j + k];
                h4[j] += wk * p12[j + k];
            }
        }
        int ob = r * TILE + c4 * 4;
        *(float4*)&hbuf[0][ob] = make_float4(h0[0], h0[1], h0[2], h0[3]);
        *(float4*)&hbuf[1][ob] = make_float4(h1[0], h1[1], h1[2], h1[3]);
        *(float4*)&hbuf[2][ob] = make_float4(h2[0], h2[1], h2[2], h2[3]);
        *(float4*)&hbuf[3][ob] = make_float4(h3[0], h3[1], h3[2], h3[3]);
        *(float4*)&hbuf[4][ob] = make_float4(h4[0], h4[1], h4[2], h4[3]);
    }
    __syncthreads();

    // ---- stage 3: vertical blur via 14-row register window + ssim/mcs ----
    float ssim_v = 0.f, mcs_v = 0.f;
    {
        int tx = tid & 31, ty4 = tid >> 5;  // 4 consecutive y per thread
        int y0 = ty4 * 4;
        float m[5][4];
#pragma unroll
        for (int ch = 0; ch < 5; ch++) {
            float v[14];
#pragma unroll
            for (int r = 0; r < 14; r++) v[r] = hbuf[ch][(y0 + r) * TILE + tx];
#pragma unroll
            for (int j = 0; j < 4; j++) {
                float s = 0.f;
#pragma unroll
                for (int k = 0; k < 11; k++) s += gw.w[k] * v[j + k];
                m[ch][j] = s;
            }
        }
#pragma unroll
        for (int j = 0; j < 4; j++) {
            float mu1 = m[0][j], mu2 = m[1][j];
            float mu1sq = mu1 * mu1, mu2sq = mu2 * mu2, mu12 = mu1 * mu2;
            float sg11 = m[2][j] - mu1sq;
            float sg22 = m[3][j] - mu2sq;
            float sg12 = m[4][j] - mu12;
            float mcs  = (2.f * sg12 + C2_) / (sg11 + sg22 + C2_);
            float ssim = ((2.f * mu12 + C1_) / (mu1sq + mu2sq + C1_)) * mcs;
            ssim_v += ssim;
            mcs_v  += mcs;
        }
    }

    // ---- block reduction + slotted atomics ----
#pragma unroll
    for (int off = 32; off > 0; off >>= 1) {
        ssim_v += __shfl_down(ssim_v, off);
        mcs_v  += __shfl_down(mcs_v, off);
    }
    int wave = tid >> 6, lane = tid & 63;
    if (lane == 0) { red_s[wave] = ssim_v; red_m[wave] = mcs_v; }
    __syncthreads();
    if (tid == 0) {
        float S = red_s[0] + red_s[1] + red_s[2] + red_s[3];
        float M = red_m[0] + red_m[1] + red_m[2] + red_m[3];
        unsigned lb = blockIdx.x + gridDim.x * (blockIdx.y + gridDim.y * blockIdx.z);
        unsigned slot = lb & (NSLOT - 1);
        atomicAdd(&acc[slot], S);
        atomicAdd(&acc[NSLOT + slot], M);
    }
}

// acc layout: level l, quantity q (0=ssim,1=mcs) at acc[(2*l+q)*NSLOT + slot]
__global__ void finalize_kernel(const float* __restrict__ acc,
                                float* __restrict__ out, int N) {
    int lane = threadIdx.x & 63;
    float sums[10];
#pragma unroll
    for (int q = 0; q < 10; q++) {
        float v = acc[q * NSLOT + lane];
#pragma unroll
        for (int off = 32; off > 0; off >>= 1) v += __shfl_down(v, off);
        sums[q] = v;
    }
    if (blockIdx.x == 0 && threadIdx.x == 0) {
        const float wts[5] = {0.0448f, 0.2856f, 0.3001f, 0.2363f, 0.1333f};
        float r = 1.f;
#pragma unroll
        for (int l = 0; l < 5; l++) {
            int Hl = 512 >> l;
            float cnt = (float)N * (float)Hl * (float)Hl;
            float ssim_m = sums[2 * l] / cnt;
            float mcs_m  = sums[2 * l + 1] / cnt;
            if (l < 4) r *= powf(mcs_m, wts[l]);
            else       r *= powf(ssim_m, wts[4]);
        }
        out[0] = r;
    }
}

extern "C" void kernel_launch(void* const* d_in, const int* in_sizes, int n_in,
                              void* d_out, int out_size, void* d_ws, size_t ws_size,
                              hipStream_t stream) {
    const float* img1 = (const float*)d_in[0];
    const float* img2 = (const float*)d_in[1];
    float* out = (float*)d_out;
    const int HW0 = 512 * 512;
    const int N = in_sizes[0] / HW0;  // 32

    // ws layout: accumulator slots (10*NSLOT floats), then pyramid buffers.
    float* base = (float*)d_ws;
    float* acc = base;
    size_t cur = 10 * NSLOT;
    const float* l1[5];
    const float* l2[5];
    float* w1[5] = {nullptr};
    float* w2[5] = {nullptr};
    l1[0] = img1;
    l2[0] = img2;
    for (int l = 1; l < 5; l++) {
        int Hl = 512 >> l;
        size_t hw = (size_t)Hl * Hl;
        w1[l] = base + cur; cur += (size_t)N * hw;
        w2[l] = base + cur; cur += (size_t)N * hw;
        l1[l] = w1[l];
        l2[l] = w2[l];
    }

    // zero the accumulator slots (ws is poisoned before every timed launch)
    hipMemsetAsync(acc, 0, 10 * NSLOT * sizeof(float), stream);

    // gaussian window (host-computed each call; cheap, capture-safe)
    GaussW gw;
    {
        double g[11], sum = 0.0;
        for (int i = 0; i < 11; i++) {
            double x = (double)(i - 5);
            g[i] = exp(-(x * x) / (2.0 * 1.5 * 1.5));
            sum += g[i];
        }
        for (int i = 0; i < 11; i++) gw.w[i] = (float)(g[i] / sum);
    }

    for (int l = 0; l < 5; l++) {
        int Hl = 512 >> l;
        dim3 grid(Hl / TILE, Hl / TILE, N);
        ssim_level_kernel<<<grid, 256, 0, stream>>>(
            l1[l], l2[l], Hl, acc + 2 * l * NSLOT,
            (l < 4) ? w1[l + 1] : nullptr,
            (l < 4) ? w2[l + 1] : nullptr, gw);
    }
    finalize_kernel<<<1, 64, 0, stream>>>(acc, out, N);
}

// Round 4
// 177.685 us; speedup vs baseline: 6.9506x; 1.3032x over previous
//
#include <hip/hip_runtime.h>
#include <math.h>

// MS-SSIM, 5 levels, fp32, N=32 images of 512x512.
// R4: (a) drop raw-pixel LDS stage — horizontal blur reads 20-float windows
//     straight from global (L1-resident), LDS 41.9->26.9KB, 1 barrier fewer,
//     occupancy 2.4 -> ~4-5 blocks/CU;
//     (b) one hierarchical pyramid kernel (block = 128x128 region, pools
//     levels 1-4 via LDS, no cross-block deps) + ONE mega-SSIM dispatch over
//     all 5 levels (grid 341 x N) so small levels run at full GPU width.

#define TILE 32
#define HALO 5
#define SROWS 42   // TILE + 2*HALO
#define NSLOT 64

struct GaussW { float w[11]; };

#define C1_ (0.01f * 0.01f)
#define C2_ (0.03f * 0.03f)

// ---------------- pyramid: levels 1..4 in one launch ----------------
__global__ __launch_bounds__(256) void pyramid_kernel(
        const float* __restrict__ in1, const float* __restrict__ in2,
        float* __restrict__ l1a, float* __restrict__ l1b,
        float* __restrict__ l2a, float* __restrict__ l2b,
        float* __restrict__ l3a, float* __restrict__ l3b,
        float* __restrict__ l4a, float* __restrict__ l4b) {
    __shared__ float b1[64 * 64], b2[64 * 64];
    __shared__ float c1[32 * 32], c2[32 * 32];
    __shared__ float d1[16 * 16], d2[16 * 16];
    const int tid = threadIdx.x;
    const int n = blockIdx.y;
    const int rx = blockIdx.x & 3, ry = blockIdx.x >> 2;  // 4x4 regions
    const float* p1 = in1 + (size_t)n * 512 * 512;
    const float* p2 = in2 + (size_t)n * 512 * 512;

    // L1: 64x64 region outputs (2 per item)
    for (int i = tid; i < 64 * 32; i += 256) {
        int oy = i >> 5, oxp = i & 31;
        int gy = ry * 128 + 2 * oy, gx = rx * 128 + 4 * oxp;
        float4 r10 = *(const float4*)(p1 + (size_t)gy * 512 + gx);
        float4 r11 = *(const float4*)(p1 + (size_t)(gy + 1) * 512 + gx);
        float4 r20 = *(const float4*)(p2 + (size_t)gy * 512 + gx);
        float4 r21 = *(const float4*)(p2 + (size_t)(gy + 1) * 512 + gx);
        float2 o1 = make_float2(0.25f * (r10.x + r10.y + r11.x + r11.y),
                                0.25f * (r10.z + r10.w + r11.z + r11.w));
        float2 o2 = make_float2(0.25f * (r20.x + r20.y + r21.x + r21.y),
                                0.25f * (r20.z + r20.w + r21.z + r21.w));
        *(float2*)&b1[oy * 64 + 2 * oxp] = o1;
        *(float2*)&b2[oy * 64 + 2 * oxp] = o2;
        size_t o = (size_t)n * 256 * 256 + (size_t)(ry * 64 + oy) * 256 + rx * 64 + 2 * oxp;
        *(float2*)&l1a[o] = o1;
        *(float2*)&l1b[o] = o2;
    }
    __syncthreads();

    // L2: 32x32
    for (int i = tid; i < 32 * 16; i += 256) {
        int oy = i >> 4, oxp = i & 15;
        float4 r10 = *(const float4*)&b1[(2 * oy) * 64 + 4 * oxp];
        float4 r11 = *(const float4*)&b1[(2 * oy + 1) * 64 + 4 * oxp];
        float4 r20 = *(const float4*)&b2[(2 * oy) * 64 + 4 * oxp];
        float4 r21 = *(const float4*)&b2[(2 * oy + 1) * 64 + 4 * oxp];
        float2 o1 = make_float2(0.25f * (r10.x + r10.y + r11.x + r11.y),
                                0.25f * (r10.z + r10.w + r11.z + r11.w));
        float2 o2 = make_float2(0.25f * (r20.x + r20.y + r21.x + r21.y),
                                0.25f * (r20.z + r20.w + r21.z + r21.w));
        *(float2*)&c1[oy * 32 + 2 * oxp] = o1;
        *(float2*)&c2[oy * 32 + 2 * oxp] = o2;
        size_t o = (size_t)n * 128 * 128 + (size_t)(ry * 32 + oy) * 128 + rx * 32 + 2 * oxp;
        *(float2*)&l2a[o] = o1;
        *(float2*)&l2b[o] = o2;
    }
    __syncthreads();

    // L3: 16x16
    for (int i = tid; i < 16 * 8; i += 256) {
        int oy = i >> 3, oxp = i & 7;
        float4 r10 = *(const float4*)&c1[(2 * oy) * 32 + 4 * oxp];
        float4 r11 = *(const float4*)&c1[(2 * oy + 1) * 32 + 4 * oxp];
        float4 r20 = *(const float4*)&c2[(2 * oy) * 32 + 4 * oxp];
        float4 r21 = *(const float4*)&c2[(2 * oy + 1) * 32 + 4 * oxp];
        float2 o1 = make_float2(0.25f * (r10.x + r10.y + r11.x + r11.y),
                                0.25f * (r10.z + r10.w + r11.z + r11.w));
        float2 o2 = make_float2(0.25f * (r20.x + r20.y + r21.x + r21.y),
                                0.25f * (r20.z + r20.w + r21.z + r21.w));
        *(float2*)&d1[oy * 16 + 2 * oxp] = o1;
        *(float2*)&d2[oy * 16 + 2 * oxp] = o2;
        size_t o = (size_t)n * 64 * 64 + (size_t)(ry * 16 + oy) * 64 + rx * 16 + 2 * oxp;
        *(float2*)&l3a[o] = o1;
        *(float2*)&l3b[o] = o2;
    }
    __syncthreads();

    // L4: 8x8 (global write only)
    for (int i = tid; i < 8 * 4; i += 256) {
        int oy = i >> 2, oxp = i & 3;
        float4 r10 = *(const float4*)&d1[(2 * oy) * 16 + 4 * oxp];
        float4 r11 = *(const float4*)&d1[(2 * oy + 1) * 16 + 4 * oxp];
        float4 r20 = *(const float4*)&d2[(2 * oy) * 16 + 4 * oxp];
        float4 r21 = *(const float4*)&d2[(2 * oy + 1) * 16 + 4 * oxp];
        float2 o1 = make_float2(0.25f * (r10.x + r10.y + r11.x + r11.y),
                                0.25f * (r10.z + r10.w + r11.z + r11.w));
        float2 o2 = make_float2(0.25f * (r20.x + r20.y + r21.x + r21.y),
                                0.25f * (r20.z + r20.w + r21.z + r21.w));
        size_t o = (size_t)n * 32 * 32 + (size_t)(ry * 8 + oy) * 32 + rx * 8 + 2 * oxp;
        *(float2*)&l4a[o] = o1;
        *(float2*)&l4b[o] = o2;
    }
}

// ---------------- mega-SSIM: all 5 levels in one dispatch ----------------
// grid.x tile id: [0,256) L0, [256,320) L1, [320,336) L2, [336,340) L3, 340 L4
__global__ __launch_bounds__(256, 4) void ssim_all_kernel(
        const float* __restrict__ i0a, const float* __restrict__ i0b,
        const float* __restrict__ l1a, const float* __restrict__ l1b,
        const float* __restrict__ l2a, const float* __restrict__ l2b,
        const float* __restrict__ l3a, const float* __restrict__ l3b,
        const float* __restrict__ l4a, const float* __restrict__ l4b,
        float* __restrict__ acc,  // [5][2][NSLOT]
        GaussW gw) {
    __shared__ float hbuf[5][SROWS * TILE];  // 26880 B
    __shared__ float red_s[4], red_m[4];

    const int tid = threadIdx.x;
    const int t = blockIdx.x;
    const int n = blockIdx.y;
    int level, idx, W;
    const float* base1;
    const float* base2;
    if (t < 256)      { level = 0; idx = t;       W = 512; base1 = i0a; base2 = i0b; }
    else if (t < 320) { level = 1; idx = t - 256; W = 256; base1 = l1a; base2 = l1b; }
    else if (t < 336) { level = 2; idx = t - 320; W = 128; base1 = l2a; base2 = l2b; }
    else if (t < 340) { level = 3; idx = t - 336; W = 64;  base1 = l3a; base2 = l3b; }
    else              { level = 4; idx = 0;       W = 32;  base1 = l4a; base2 = l4b; }
    const int tpr = W >> 5;
    const int sh = 31 - __clz(tpr);
    const int tile_x = (idx & (tpr - 1)) << 5;
    const int tile_y = (idx >> sh) << 5;
    const float* p1 = base1 + (size_t)n * W * W;
    const float* p2 = base2 + (size_t)n * W * W;

    // ---- stage A: horizontal blur straight from global (aligned float4) ----
    for (int it = tid; it < SROWS * 8; it += 256) {
        int r = it >> 3, c4 = it & 7;
        int gy = tile_y + r - HALO;
        int gx0 = tile_x + (c4 << 2) - 8;
        bool rowok = (gy >= 0) && (gy < W);
        const float* row1 = p1 + (size_t)gy * W;
        const float* row2 = p2 + (size_t)gy * W;
        float a1[20], a2[20];
#pragma unroll
        for (int q = 0; q < 5; q++) {
            int g = gx0 + q * 4;
            bool ok = rowok && (g >= 0) && (g + 4 <= W);
            float4 v1 = ok ? *(const float4*)(row1 + g) : make_float4(0.f, 0.f, 0.f, 0.f);
            float4 v2 = ok ? *(const float4*)(row2 + g) : make_float4(0.f, 0.f, 0.f, 0.f);
            a1[q * 4 + 0] = v1.x; a1[q * 4 + 1] = v1.y; a1[q * 4 + 2] = v1.z; a1[q * 4 + 3] = v1.w;
            a2[q * 4 + 0] = v2.x; a2[q * 4 + 1] = v2.y; a2[q * 4 + 2] = v2.z; a2[q * 4 + 3] = v2.w;
        }
        // products for window indices 3..16
        float p11[14], p22[14], p12[14];
#pragma unroll
        for (int i = 0; i < 14; i++) {
            float u = a1[i + 3], v = a2[i + 3];
            p11[i] = u * u;
            p22[i] = v * v;
            p12[i] = u * v;
        }
        float h0[4] = {0, 0, 0, 0}, h1[4] = {0, 0, 0, 0}, h2[4] = {0, 0, 0, 0};
        float h3[4] = {0, 0, 0, 0}, h4[4] = {0, 0, 0, 0};
#pragma unroll
        for (int k = 0; k < 11; k++) {
            float wk = gw.w[k];
#pragma unroll
            for (int j = 0; j < 4; j++) {
                h0[j] += wk * a1[3 + j + k];
                h1[j] += wk * a2[3 + j + k];
                h2[j] += wk * p11[j + k];
                h3[j] += wk * p22[j + k];
                h4[j] += wk * p12[j + k];
            }
        }
        int ob = r * TILE + (c4 << 2);
        *(float4*)&hbuf[0][ob] = make_float4(h0[0], h0[1], h0[2], h0[3]);
        *(float4*)&hbuf[1][ob] = make_float4(h1[0], h1[1], h1[2], h1[3]);
        *(float4*)&hbuf[2][ob] = make_float4(h2[0], h2[1], h2[2], h2[3]);
        *(float4*)&hbuf[3][ob] = make_float4(h3[0], h3[1], h3[2], h3[3]);
        *(float4*)&hbuf[4][ob] = make_float4(h4[0], h4[1], h4[2], h4[3]);
    }
    __syncthreads();

    // ---- stage B: vertical blur via 14-row register window + ssim/mcs ----
    float ssim_v = 0.f, mcs_v = 0.f;
    {
        int tx = tid & 31, ty4 = tid >> 5;
        int y0 = ty4 * 4;
        float m[5][4];
#pragma unroll
        for (int ch = 0; ch < 5; ch++) {
            float v[14];
#pragma unroll
            for (int r = 0; r < 14; r++) v[r] = hbuf[ch][(y0 + r) * TILE + tx];
#pragma unroll
            for (int j = 0; j < 4; j++) {
                float s = 0.f;
#pragma unroll
                for (int k = 0; k < 11; k++) s += gw.w[k] * v[j + k];
                m[ch][j] = s;
            }
        }
#pragma unroll
        for (int j = 0; j < 4; j++) {
            float mu1 = m[0][j], mu2 = m[1][j];
            float mu1sq = mu1 * mu1, mu2sq = mu2 * mu2, mu12 = mu1 * mu2;
            float sg11 = m[2][j] - mu1sq;
            float sg22 = m[3][j] - mu2sq;
            float sg12 = m[4][j] - mu12;
            float mcs  = (2.f * sg12 + C2_) / (sg11 + sg22 + C2_);
            float ssim = ((2.f * mu12 + C1_) / (mu1sq + mu2sq + C1_)) * mcs;
            ssim_v += ssim;
            mcs_v  += mcs;
        }
    }

    // ---- reduction + slotted atomics ----
#pragma unroll
    for (int off = 32; off > 0; off >>= 1) {
        ssim_v += __shfl_down(ssim_v, off);
        mcs_v  += __shfl_down(mcs_v, off);
    }
    int wave = tid >> 6, lane = tid & 63;
    if (lane == 0) { red_s[wave] = ssim_v; red_m[wave] = mcs_v; }
    __syncthreads();
    if (tid == 0) {
        float S = red_s[0] + red_s[1] + red_s[2] + red_s[3];
        float M = red_m[0] + red_m[1] + red_m[2] + red_m[3];
        unsigned slot = ((unsigned)(t << 5) + (unsigned)n) & (NSLOT - 1);
        float* a = acc + level * 2 * NSLOT;
        atomicAdd(&a[slot], S);
        atomicAdd(&a[NSLOT + slot], M);
    }
}

// acc layout: level l, quantity q (0=ssim,1=mcs) at acc[(2*l+q)*NSLOT + slot]
__global__ void finalize_kernel(const float* __restrict__ acc,
                                float* __restrict__ out, int N) {
    int lane = threadIdx.x & 63;
    float sums[10];
#pragma unroll
    for (int q = 0; q < 10; q++) {
        float v = acc[q * NSLOT + lane];
#pragma unroll
        for (int off = 32; off > 0; off >>= 1) v += __shfl_down(v, off);
        sums[q] = v;
    }
    if (blockIdx.x == 0 && threadIdx.x == 0) {
        const float wts[5] = {0.0448f, 0.2856f, 0.3001f, 0.2363f, 0.1333f};
        float r = 1.f;
#pragma unroll
        for (int l = 0; l < 5; l++) {
            int Hl = 512 >> l;
            float cnt = (float)N * (float)Hl * (float)Hl;
            float ssim_m = sums[2 * l] / cnt;
            float mcs_m  = sums[2 * l + 1] / cnt;
            if (l < 4) r *= powf(mcs_m, wts[l]);
            else       r *= powf(ssim_m, wts[4]);
        }
        out[0] = r;
    }
}

extern "C" void kernel_launch(void* const* d_in, const int* in_sizes, int n_in,
                              void* d_out, int out_size, void* d_ws, size_t ws_size,
                              hipStream_t stream) {
    const float* img1 = (const float*)d_in[0];
    const float* img2 = (const float*)d_in[1];
    float* out = (float*)d_out;
    const int HW0 = 512 * 512;
    const int N = in_sizes[0] / HW0;  // 32

    // ws: acc slots (10*NSLOT floats), then pyramid levels 1..4 (both imgs).
    float* base = (float*)d_ws;
    float* acc = base;
    size_t cur = 10 * NSLOT;
    float* w1[5] = {nullptr};
    float* w2[5] = {nullptr};
    for (int l = 1; l < 5; l++) {
        int Hl = 512 >> l;
        size_t hw = (size_t)Hl * Hl;
        w1[l] = base + cur; cur += (size_t)N * hw;
        w2[l] = base + cur; cur += (size_t)N * hw;
    }

    hipMemsetAsync(acc, 0, 10 * NSLOT * sizeof(float), stream);

    GaussW gw;
    {
        double g[11], sum = 0.0;
        for (int i = 0; i < 11; i++) {
            double x = (double)(i - 5);
            g[i] = exp(-(x * x) / (2.0 * 1.5 * 1.5));
            sum += g[i];
        }
        for (int i = 0; i < 11; i++) gw.w[i] = (float)(g[i] / sum);
    }

    pyramid_kernel<<<dim3(16, N), 256, 0, stream>>>(
        img1, img2, w1[1], w2[1], w1[2], w2[2], w1[3], w2[3], w1[4], w2[4]);

    ssim_all_kernel<<<dim3(341, N), 256, 0, stream>>>(
        img1, img2, w1[1], w2[1], w1[2], w2[2], w1[3], w2[3], w1[4], w2[4],
        acc, gw);

    finalize_kernel<<<1, 64, 0, stream>>>(acc, out, N);
}

// Round 5
// 173.056 us; speedup vs baseline: 7.1365x; 1.0267x over previous
//
#include <hip/hip_runtime.h>
#include <math.h>

// MS-SSIM, 5 levels, fp32, N=32 of 512x512.
// R5: (a) pyramid blocks fused INTO the L0-SSIM dispatch (independent blocks,
//     64x64 regions x 2048 blocks) so the ~90us serial pyramid+gap time hides
//     under the VALU-bound L0 work; L1-4 SSIM in a second small dispatch.
//     (b) packed fp32 (v2f -> v_pk_fma_f32): {img1,img2} and {x^2,y^2} channel
//     pairs in both blur passes (~40% fewer blur FMAs).
//     (c) wave-uniform interior fast path: no per-float4 bounds checks.

typedef float v2f __attribute__((ext_vector_type(2)));

#define TILE 32
#define HALO 5
#define SROWS 42   // TILE + 2*HALO
#define NSLOT 64

struct GaussW { float w[11]; };

#define C1_ (0.01f * 0.01f)
#define C2_ (0.03f * 0.03f)

// smem carve (floats): hb01 v2f[1344] = 2688f | hb23 2688f | hb4 1344f | red 8f
#define SMEM_FLOATS 6728

__device__ __forceinline__ void ssim_tile(
        const float* __restrict__ p1, const float* __restrict__ p2,
        int W, int tile_x, int tile_y, const GaussW& gw,
        float* __restrict__ accL, unsigned slot, float* smem, int tid) {
    v2f* hb01 = (v2f*)smem;                     // [SROWS*TILE]
    v2f* hb23 = (v2f*)(smem + 2 * SROWS * TILE);
    float* hb4 = smem + 4 * SROWS * TILE;
    float* red = smem + 5 * SROWS * TILE;       // [8]

    const bool xfast = (tile_x >= 8) && (tile_x + TILE + 8 <= W);

    // ---- stage A: horizontal blur from global, packed channels ----
    for (int it = tid; it < SROWS * 8; it += 256) {
        int r = it >> 3, c4 = it & 7;
        int gy = tile_y + r - HALO;
        int gx0 = tile_x + (c4 << 2) - 8;
        bool rowok = (gy >= 0) && (gy < W);
        const float* row1 = p1 + (size_t)gy * W;
        const float* row2 = p2 + (size_t)gy * W;
        float a1[20], a2[20];
#pragma unroll
        for (int i = 0; i < 20; i++) { a1[i] = 0.f; a2[i] = 0.f; }
        if (xfast) {
            if (rowok) {
#pragma unroll
                for (int q = 0; q < 5; q++) {
                    float4 v1 = *(const float4*)(row1 + gx0 + q * 4);
                    float4 v2v = *(const float4*)(row2 + gx0 + q * 4);
                    a1[q*4+0] = v1.x;  a1[q*4+1] = v1.y;  a1[q*4+2] = v1.z;  a1[q*4+3] = v1.w;
                    a2[q*4+0] = v2v.x; a2[q*4+1] = v2v.y; a2[q*4+2] = v2v.z; a2[q*4+3] = v2v.w;
                }
            }
        } else {
#pragma unroll
            for (int q = 0; q < 5; q++) {
                int g = gx0 + q * 4;
                if (rowok && g >= 0 && g + 4 <= W) {
                    float4 v1 = *(const float4*)(row1 + g);
                    float4 v2v = *(const float4*)(row2 + g);
                    a1[q*4+0] = v1.x;  a1[q*4+1] = v1.y;  a1[q*4+2] = v1.z;  a1[q*4+3] = v1.w;
                    a2[q*4+0] = v2v.x; a2[q*4+1] = v2v.y; a2[q*4+2] = v2v.z; a2[q*4+3] = v2v.w;
                }
            }
        }
        v2f A[20];
#pragma unroll
        for (int i = 0; i < 20; i++) A[i] = (v2f){a1[i], a2[i]};
        v2f P[14];
        float p12[14];
#pragma unroll
        for (int i = 0; i < 14; i++) {
            v2f u = A[i + 3];
            P[i] = u * u;
            p12[i] = u.x * u.y;
        }
        v2f h01[4] = {(v2f)(0.f), (v2f)(0.f), (v2f)(0.f), (v2f)(0.f)};
        v2f h23[4] = {(v2f)(0.f), (v2f)(0.f), (v2f)(0.f), (v2f)(0.f)};
        float h4[4] = {0.f, 0.f, 0.f, 0.f};
#pragma unroll
        for (int k = 0; k < 11; k++) {
            float wk = gw.w[k];
#pragma unroll
            for (int j = 0; j < 4; j++) {
                h01[j] += wk * A[3 + j + k];
                h23[j] += wk * P[j + k];
                h4[j]  += wk * p12[j + k];
            }
        }
        int ob = r * TILE + (c4 << 2);
#pragma unroll
        for (int j = 0; j < 4; j++) { hb01[ob + j] = h01[j]; hb23[ob + j] = h23[j]; }
        *(float4*)&hb4[ob] = make_float4(h4[0], h4[1], h4[2], h4[3]);
    }
    __syncthreads();

    // ---- stage B: vertical blur (packed) + ssim/mcs ----
    float ssim_v = 0.f, mcs_v = 0.f;
    {
        int tx = tid & 31, y0 = (tid >> 5) * 4;
        v2f m01[4], m23[4];
        float m4[4];
        {
            v2f v[14];
#pragma unroll
            for (int r = 0; r < 14; r++) v[r] = hb01[(y0 + r) * TILE + tx];
#pragma unroll
            for (int j = 0; j < 4; j++) {
                v2f s = (v2f)(0.f);
#pragma unroll
                for (int k = 0; k < 11; k++) s += gw.w[k] * v[j + k];
                m01[j] = s;
            }
        }
        {
            v2f v[14];
#pragma unroll
            for (int r = 0; r < 14; r++) v[r] = hb23[(y0 + r) * TILE + tx];
#pragma unroll
            for (int j = 0; j < 4; j++) {
                v2f s = (v2f)(0.f);
#pragma unroll
                for (int k = 0; k < 11; k++) s += gw.w[k] * v[j + k];
                m23[j] = s;
            }
        }
        {
            float v[14];
#pragma unroll
            for (int r = 0; r < 14; r++) v[r] = hb4[(y0 + r) * TILE + tx];
#pragma unroll
            for (int j = 0; j < 4; j++) {
                float s = 0.f;
#pragma unroll
                for (int k = 0; k < 11; k++) s += gw.w[k] * v[j + k];
                m4[j] = s;
            }
        }
#pragma unroll
        for (int j = 0; j < 4; j++) {
            float mu1 = m01[j].x, mu2 = m01[j].y;
            float mu1sq = mu1 * mu1, mu2sq = mu2 * mu2, mu12 = mu1 * mu2;
            float sg11 = m23[j].x - mu1sq;
            float sg22 = m23[j].y - mu2sq;
            float sg12 = m4[j] - mu12;
            float mcs  = (2.f * sg12 + C2_) / (sg11 + sg22 + C2_);
            float ssim = ((2.f * mu12 + C1_) / (mu1sq + mu2sq + C1_)) * mcs;
            ssim_v += ssim;
            mcs_v  += mcs;
        }
    }

    // ---- reduction + slotted atomic ----
#pragma unroll
    for (int off = 32; off > 0; off >>= 1) {
        ssim_v += __shfl_down(ssim_v, off);
        mcs_v  += __shfl_down(mcs_v, off);
    }
    int wave = tid >> 6, lane = tid & 63;
    if (lane == 0) { red[wave] = ssim_v; red[4 + wave] = mcs_v; }
    __syncthreads();
    if (tid == 0) {
        float S = red[0] + red[1] + red[2] + red[3];
        float M = red[4] + red[5] + red[6] + red[7];
        atomicAdd(&accL[slot], S);
        atomicAdd(&accL[NSLOT + slot], M);
    }
}

// pyramid region: 64x64 of L0 -> 32x32 L1, 16x16 L2, 8x8 L3, 4x4 L4
__device__ __forceinline__ void pyramid_region(
        const float* __restrict__ in1, const float* __restrict__ in2,
        int n, int reg,
        float* __restrict__ l1a, float* __restrict__ l1b,
        float* __restrict__ l2a, float* __restrict__ l2b,
        float* __restrict__ l3a, float* __restrict__ l3b,
        float* __restrict__ l4a, float* __restrict__ l4b,
        float* smem, int tid) {
    float* b1 = smem;          // 32*32
    float* b2 = smem + 1024;
    float* c1 = smem + 2048;   // 16*16
    float* c2 = smem + 2304;
    float* d1 = smem + 2560;   // 8*8
    float* d2 = smem + 2624;
    const int rx = reg & 7, ry = reg >> 3;
    const float* p1 = in1 + (size_t)n * 512 * 512;
    const float* p2 = in2 + (size_t)n * 512 * 512;

    // L1: 32x32 outputs (items 32 rows x 16 quads, 2 iters)
    for (int i = tid; i < 32 * 16; i += 256) {
        int oy = i >> 4, oxp = i & 15;
        int gy = ry * 64 + 2 * oy, gx = rx * 64 + 4 * oxp;
        float4 r10 = *(const float4*)(p1 + (size_t)gy * 512 + gx);
        float4 r11 = *(const float4*)(p1 + (size_t)(gy + 1) * 512 + gx);
        float4 r20 = *(const float4*)(p2 + (size_t)gy * 512 + gx);
        float4 r21 = *(const float4*)(p2 + (size_t)(gy + 1) * 512 + gx);
        float2 o1 = make_float2(0.25f * (r10.x + r10.y + r11.x + r11.y),
                                0.25f * (r10.z + r10.w + r11.z + r11.w));
        float2 o2 = make_float2(0.25f * (r20.x + r20.y + r21.x + r21.y),
                                0.25f * (r20.z + r20.w + r21.z + r21.w));
        *(float2*)&b1[oy * 32 + 2 * oxp] = o1;
        *(float2*)&b2[oy * 32 + 2 * oxp] = o2;
        size_t o = (size_t)n * 256 * 256 + (size_t)(ry * 32 + oy) * 256 + rx * 32 + 2 * oxp;
        *(float2*)&l1a[o] = o1;
        *(float2*)&l1b[o] = o2;
    }
    __syncthreads();
    // L2: 16x16
    if (tid < 16 * 8) {
        int oy = tid >> 3, oxp = tid & 7;
        float4 r10 = *(const float4*)&b1[(2 * oy) * 32 + 4 * oxp];
        float4 r11 = *(const float4*)&b1[(2 * oy + 1) * 32 + 4 * oxp];
        float4 r20 = *(const float4*)&b2[(2 * oy) * 32 + 4 * oxp];
        float4 r21 = *(const float4*)&b2[(2 * oy + 1) * 32 + 4 * oxp];
        float2 o1 = make_float2(0.25f * (r10.x + r10.y + r11.x + r11.y),
                                0.25f * (r10.z + r10.w + r11.z + r11.w));
        float2 o2 = make_float2(0.25f * (r20.x + r20.y + r21.x + r21.y),
                                0.25f * (r20.z + r20.w + r21.z + r21.w));
        *(float2*)&c1[oy * 16 + 2 * oxp] = o1;
        *(float2*)&c2[oy * 16 + 2 * oxp] = o2;
        size_t o = (size_t)n * 128 * 128 + (size_t)(ry * 16 + oy) * 128 + rx * 16 + 2 * oxp;
        *(float2*)&l2a[o] = o1;
        *(float2*)&l2b[o] = o2;
    }
    __syncthreads();
    // L3: 8x8
    if (tid < 8 * 4) {
        int oy = tid >> 2, oxp = tid & 3;
        float4 r10 = *(const float4*)&c1[(2 * oy) * 16 + 4 * oxp];
        float4 r11 = *(const float4*)&c1[(2 * oy + 1) * 16 + 4 * oxp];
        float4 r20 = *(const float4*)&c2[(2 * oy) * 16 + 4 * oxp];
        float4 r21 = *(const float4*)&c2[(2 * oy + 1) * 16 + 4 * oxp];
        float2 o1 = make_float2(0.25f * (r10.x + r10.y + r11.x + r11.y),
                                0.25f * (r10.z + r10.w + r11.z + r11.w));
        float2 o2 = make_float2(0.25f * (r20.x + r20.y + r21.x + r21.y),
                                0.25f * (r20.z + r20.w + r21.z + r21.w));
        *(float2*)&d1[oy * 8 + 2 * oxp] = o1;
        *(float2*)&d2[oy * 8 + 2 * oxp] = o2;
        size_t o = (size_t)n * 64 * 64 + (size_t)(ry * 8 + oy) * 64 + rx * 8 + 2 * oxp;
        *(float2*)&l3a[o] = o1;
        *(float2*)&l3b[o] = o2;
    }
    __syncthreads();
    // L4: 4x4
    if (tid < 4 * 2) {
        int oy = tid >> 1, oxp = tid & 1;
        float4 r10 = *(const float4*)&d1[(2 * oy) * 8 + 4 * oxp];
        float4 r11 = *(const float4*)&d1[(2 * oy + 1) * 8 + 4 * oxp];
        float4 r20 = *(const float4*)&d2[(2 * oy) * 8 + 4 * oxp];
        float4 r21 = *(const float4*)&d2[(2 * oy + 1) * 8 + 4 * oxp];
        float2 o1 = make_float2(0.25f * (r10.x + r10.y + r11.x + r11.y),
                                0.25f * (r10.z + r10.w + r11.z + r11.w));
        float2 o2 = make_float2(0.25f * (r20.x + r20.y + r21.x + r21.y),
                                0.25f * (r20.z + r20.w + r21.z + r21.w));
        size_t o = (size_t)n * 32 * 32 + (size_t)(ry * 4 + oy) * 32 + rx * 4 + 2 * oxp;
        *(float2*)&l4a[o] = o1;
        *(float2*)&l4b[o] = o2;
    }
}

// D1: t<64 pyramid region, t in [64,320) L0 ssim tile
__global__ __launch_bounds__(256, 4) void d1_kernel(
        const float* __restrict__ i0a, const float* __restrict__ i0b,
        float* __restrict__ l1a, float* __restrict__ l1b,
        float* __restrict__ l2a, float* __restrict__ l2b,
        float* __restrict__ l3a, float* __restrict__ l3b,
        float* __restrict__ l4a, float* __restrict__ l4b,
        float* __restrict__ acc, GaussW gw) {
    __shared__ float smem[SMEM_FLOATS];
    const int tid = threadIdx.x;
    const int t = blockIdx.x;
    const int n = blockIdx.y;
    if (t < 64) {
        pyramid_region(i0a, i0b, n, t, l1a, l1b, l2a, l2b, l3a, l3b, l4a, l4b,
                       smem, tid);
    } else {
        int idx = t - 64;
        int tile_x = (idx & 15) << 5;
        int tile_y = (idx >> 4) << 5;
        const float* p1 = i0a + (size_t)n * 512 * 512;
        const float* p2 = i0b + (size_t)n * 512 * 512;
        unsigned slot = ((unsigned)(idx << 5) + (unsigned)n) & (NSLOT - 1);
        ssim_tile(p1, p2, 512, tile_x, tile_y, gw, acc, slot, smem, tid);
    }
}

// D2: ssim for levels 1..4. t: [0,64) L1, [64,80) L2, [80,84) L3, 84 L4
__global__ __launch_bounds__(256, 4) void d2_kernel(
        const float* __restrict__ l1a, const float* __restrict__ l1b,
        const float* __restrict__ l2a, const float* __restrict__ l2b,
        const float* __restrict__ l3a, const float* __restrict__ l3b,
        const float* __restrict__ l4a, const float* __restrict__ l4b,
        float* __restrict__ acc, GaussW gw) {
    __shared__ float smem[SMEM_FLOATS];
    const int tid = threadIdx.x;
    const int t = blockIdx.x;
    const int n = blockIdx.y;
    int level, idx, W;
    const float* base1;
    const float* base2;
    if (t < 64)      { level = 1; idx = t;      W = 256; base1 = l1a; base2 = l1b; }
    else if (t < 80) { level = 2; idx = t - 64; W = 128; base1 = l2a; base2 = l2b; }
    else if (t < 84) { level = 3; idx = t - 80; W = 64;  base1 = l3a; base2 = l3b; }
    else             { level = 4; idx = 0;      W = 32;  base1 = l4a; base2 = l4b; }
    const int tpr = W >> 5;
    const int sh = 31 - __clz(tpr);
    const int tile_x = (idx & (tpr - 1)) << 5;
    const int tile_y = (idx >> sh) << 5;
    const float* p1 = base1 + (size_t)n * W * W;
    const float* p2 = base2 + (size_t)n * W * W;
    unsigned slot = ((unsigned)(t << 5) + (unsigned)n) & (NSLOT - 1);
    ssim_tile(p1, p2, W, tile_x, tile_y, gw, acc + level * 2 * NSLOT, slot,
              smem, tid);
}

// acc layout: level l, quantity q (0=ssim,1=mcs) at acc[(2*l+q)*NSLOT + slot]
__global__ void finalize_kernel(const float* __restrict__ acc,
                                float* __restrict__ out, int N) {
    int lane = threadIdx.x & 63;
    float sums[10];
#pragma unroll
    for (int q = 0; q < 10; q++) {
        float v = acc[q * NSLOT + lane];
#pragma unroll
        for (int off = 32; off > 0; off >>= 1) v += __shfl_down(v, off);
        sums[q] = v;
    }
    if (blockIdx.x == 0 && threadIdx.x == 0) {
        const float wts[5] = {0.0448f, 0.2856f, 0.3001f, 0.2363f, 0.1333f};
        float r = 1.f;
#pragma unroll
        for (int l = 0; l < 5; l++) {
            int Hl = 512 >> l;
            float cnt = (float)N * (float)Hl * (float)Hl;
            float ssim_m = sums[2 * l] / cnt;
            float mcs_m  = sums[2 * l + 1] / cnt;
            if (l < 4) r *= powf(mcs_m, wts[l]);
            else       r *= powf(ssim_m, wts[4]);
        }
        out[0] = r;
    }
}

extern "C" void kernel_launch(void* const* d_in, const int* in_sizes, int n_in,
                              void* d_out, int out_size, void* d_ws, size_t ws_size,
                              hipStream_t stream) {
    const float* img1 = (const float*)d_in[0];
    const float* img2 = (const float*)d_in[1];
    float* out = (float*)d_out;
    const int HW0 = 512 * 512;
    const int N = in_sizes[0] / HW0;  // 32

    float* base = (float*)d_ws;
    float* acc = base;
    size_t cur = 10 * NSLOT;
    float* w1[5] = {nullptr};
    float* w2[5] = {nullptr};
    for (int l = 1; l < 5; l++) {
        int Hl = 512 >> l;
        size_t hw = (size_t)Hl * Hl;
        w1[l] = base + cur; cur += (size_t)N * hw;
        w2[l] = base + cur; cur += (size_t)N * hw;
    }

    hipMemsetAsync(acc, 0, 10 * NSLOT * sizeof(float), stream);

    GaussW gw;
    {
        double g[11], sum = 0.0;
        for (int i = 0; i < 11; i++) {
            double x = (double)(i - 5);
            g[i] = exp(-(x * x) / (2.0 * 1.5 * 1.5));
            sum += g[i];
        }
        for (int i = 0; i < 11; i++) gw.w[i] = (float)(g[i] / sum);
    }

    d1_kernel<<<dim3(320, N), 256, 0, stream>>>(
        img1, img2, w1[1], w2[1], w1[2], w2[2], w1[3], w2[3], w1[4], w2[4],
        acc, gw);
    d2_kernel<<<dim3(85, N), 256, 0, stream>>>(
        w1[1], w2[1], w1[2], w2[2], w1[3], w2[3], w1[4], w2[4], acc, gw);
    finalize_kernel<<<1, 64, 0, stream>>>(acc, out, N);
}